// Round 9
// baseline (593.245 us; speedup 1.0000x reference)
//
#include <hip/hip_runtime.h>

// SimpleRNN: h_{t+1} = tanh(h_t @ H^T + x_t @ U + b); out = h_T @ A^T + c
// T=512 B=2048 IN=28 HID=198 OUT=10, all fp32.
//
// R9: R8 (fp16 single-pass recurrence, 16 waves, 4/SIMD, 13 compute waves,
// 1 x-stager wave, x@U folded as K-slot 7 with B=U) plus PAIRED-SLOT LDS
// reads: the dedup A-fragment is 512B/slot unique, but a broadcast b128
// read moves 1KB. Now lanes m<8 read slot 2p and lanes m>=8 read slot 2p+1
// (one b128 = two slots' unique data), and both MFMA A-operands are
// reassembled with v_mov_dpp row_ror:8 under bank_mask:
//   opE = dpp(mine, ror8, bank_mask=0xC): lanes 0-7 keep own (slot 2p),
//         lanes 8-15 receive partner's slot-2p row (m-8) -> dup semantics.
//   opO = dpp(mine, ror8, bank_mask=0x3): mirror for slot 2p+1.
// LDS reads halve: 104 -> 52 b128 per CU per step. C rows 8-15 remain
// duplicates of 0-7, so the R8 epilogue (rows spread over all 4 quads,
// 2 tanh + 2 ds_write_b16 per lane) is unchanged. One barrier per step.

#define T_STEPS 512
#define BATCH   2048
#define IN_DIM  28
#define HID     198
#define OUT_DIM 10
#define BB      8    // batch rows per block
#define KT      8    // 7 H k-tiles of 32 (224 >= 198) + 1 U/x slot
#define NCW     13   // compute waves / N-tiles

typedef __attribute__((ext_vector_type(8))) _Float16 half8;
typedef __attribute__((ext_vector_type(4))) float   floatx4;

__device__ __forceinline__ floatx4 mfma16(half8 a, half8 b, floatx4 c) {
    return __builtin_amdgcn_mfma_f32_16x16x32_f16(a, b, c, 0, 0, 0);
}

// tanh(x) = 1 - 2/(exp(2x)+1); exp2-based, saturates via IEEE inf/0.
__device__ __forceinline__ float fast_tanh(float x) {
    float e = __builtin_amdgcn_exp2f(x * 2.885390081777926357f); // exp(2x)
    float r = __builtin_amdgcn_rcpf(e + 1.0f);
    return __builtin_fmaf(-2.0f, r, 1.0f);
}

// Per-dword DPP row_ror:8 (lane <- lane^8 within each 16-lane row), applied
// only to lanes whose bank is in BM (others keep old = own value).
// BM=0xC: lanes 8-15 of each row updated; BM=0x3: lanes 0-7 updated.
template<int BM>
__device__ __forceinline__ half8 dpp_mix(half8 v) {
    union { half8 h; int i[4]; } u, r;
    u.h = v;
    #pragma unroll
    for (int d = 0; d < 4; ++d)
        r.i[d] = __builtin_amdgcn_update_dpp(u.i[d], u.i[d], 0x128, 0xF, BM, false);
    return r.h;
}

__global__ void __launch_bounds__(1024, 4)
rnn_kernel(const float* __restrict__ x, const float* __restrict__ H,
           const float* __restrict__ U, const float* __restrict__ A,
           const float* __restrict__ bvec, const float* __restrict__ cvec,
           float* __restrict__ out)
{
    // Dedup A-frag ping-pong: [buf][slot][chunk*8 + r8][idx], fp16, 512B/slot.
    __shared__ __align__(16) _Float16 lds_A[2][KT][32][8];   // 8 KB
    __shared__ float lds_h[BB][204];                          // final h, fp32

    const int tid  = threadIdx.x;
    const int lane = tid & 63;
    const int wv   = tid >> 6;          // wave id 0..15
    const int m    = lane & 15;         // A-row / C-col index within tile
    const int quad = lane >> 4;         // 0..3
    const int r8   = m & 7;
    const int b0   = blockIdx.x * BB;

    // zero-init both buffers (h0 = 0; phantom K rows stay 0 forever)
    {
        _Float16* p0 = &lds_A[0][0][0][0];
        for (int i = tid; i < 2*KT*32*8; i += 1024) p0[i] = (_Float16)0.0f;
    }
    __syncthreads();   // zero-fill complete before stager prologue writes

    floatx4 zero4 = {0.0f, 0.0f, 0.0f, 0.0f};

    // ---- compute-wave setup: stationary fp16 B fragments (H + U) ----
    half8 Bf[KT];
    float bias_eff = 0.0f;
    int   jcol = 0, e_ktd = 0, e_chunk8 = 0, e_idx = 0;
    bool  e_wr = false;
    if (wv < NCW) {
        jcol = wv*16 + m;                               // output column (>=198 phantom)
        bias_eff = (jcol < HID) ? bvec[jcol] : 0.0f;
        #pragma unroll
        for (int kt = 0; kt < 7; ++kt) {
            half8 f;
            #pragma unroll
            for (int idx = 0; idx < 8; ++idx) {
                int k = kt*32 + quad*8 + idx;
                float v = (jcol < HID && k < HID) ? H[jcol*HID + k] : 0.0f; // B[k][j]=H[j][k]
                f[idx] = (_Float16)v;
            }
            Bf[kt] = f;
        }
        {   // slot 7: U
            half8 f;
            #pragma unroll
            for (int idx = 0; idx < 8; ++idx) {
                int i = quad*8 + idx;
                float v = (jcol < HID && i < IN_DIM) ? U[i*HID + jcol] : 0.0f;
                f[idx] = (_Float16)v;
            }
            Bf[7] = f;
        }
        e_ktd    = jcol >> 5;
        e_chunk8 = ((jcol & 31) >> 3) * 8;
        e_idx    = jcol & 7;
        e_wr     = (jcol < HID);
    }

    // ---- epilogue row split: all 4 quads cover the 8 real C rows ----
    // quad0: regs {0,1} -> rows {0,1}; quad1: regs {0,1} -> rows {4,5};
    // quad2: regs {2,3} -> rows {2,3}; quad3: regs {2,3} -> rows {6,7}.
    const int regbase = (quad >> 1) * 2;            // 0 or 2

    // ---- stager setup (wave 15, lanes 0-31): x A-frag rows ----
    const int srow  = lane & 31;        // chunk*8 + r8
    const int sq    = srow >> 3;        // k-chunk 0..3
    const int sr8   = srow & 7;         // batch row
    const float* xrow_s = x + (size_t)(b0 + sr8) * IN_DIM + sq*8;
    const size_t tstride = (size_t)BATCH * IN_DIM;

    auto stage = [&](int tn, int buf) {
        if (lane < 32) {
            const float* p = xrow_s + (size_t)tn * tstride;
            floatx4 f0 = *(const floatx4*)p;
            floatx4 f1 = (sq < 3) ? *(const floatx4*)(p + 4) : zero4;
            half8 ax;
            ax[0] = (_Float16)f0[0]; ax[1] = (_Float16)f0[1];
            ax[2] = (_Float16)f0[2]; ax[3] = (_Float16)f0[3];
            ax[4] = (_Float16)f1[0]; ax[5] = (_Float16)f1[1];
            ax[6] = (_Float16)f1[2]; ax[7] = (_Float16)f1[3];
            *(half8*)&lds_A[buf][7][srow][0] = ax;
        }
    };

    if (wv == 15) stage(0, 0);   // prologue: x[0] into buf 0

    // paired-read base: lane m<8 reads slot 2p, m>=8 reads slot 2p+1
    const int slot_sel = (m >> 3);               // 0 or 1
    const int rd_off   = quad*8 + r8;            // row-segment within slot

    // ================= time loop =================
    #pragma unroll 1
    for (int t = 0; t < T_STEPS; ++t) {
        const int rb = t & 1;
        const int wb = rb ^ 1;

        __syncthreads();   // prior writes into rb visible; wb free to write

        if (wv < NCW) {
            // 8 MFMAs in 2 chains; 4 paired b128 reads + DPP operand rebuild.
            floatx4 acc1 = (floatx4){bias_eff, bias_eff, bias_eff, bias_eff};
            floatx4 acc2 = zero4;
            #pragma unroll
            for (int p = 0; p < 4; ++p) {
                half8 mine = *(const half8*)&lds_A[rb][2*p + slot_sel][rd_off][0];
                half8 opE  = dpp_mix<0xC>(mine);  // slot 2p operand (rows 8-15 from partner)
                half8 opO  = dpp_mix<0x3>(mine);  // slot 2p+1 operand (rows 0-7 from partner)
                acc1 = mfma16(opE, Bf[2*p],     acc1);
                acc2 = mfma16(opO, Bf[2*p + 1], acc2);
            }
            // epilogue: 2 tanh + 2 fp16 writes per lane (rows split over quads)
            if (e_wr) {
                #pragma unroll
                for (int e = 0; e < 2; ++e) {
                    const int reg = regbase + e;
                    const int row = (quad & 1) * 4 + reg;   // 0..7, all 8 covered
                    float v = fast_tanh(acc1[reg] + acc2[reg]);
                    lds_A[wb][e_ktd][e_chunk8 + row][e_idx] = (_Float16)v;
                    if (t == T_STEPS - 1) lds_h[row][jcol] = v;
                }
            }
        } else if (wv == 15) {
            const int tn = (t + 1 < T_STEPS) ? (t + 1) : t;
            stage(tn, wb);
        }
        // waves 13,14: barrier only
    }

    __syncthreads();

    // ---- output: out[b][o] = sum_k h[b][k]*A[o][k] + c[o] (tiny, scalar) ----
    if (tid < BB * OUT_DIM) {
        const int r = tid / OUT_DIM;
        const int o = tid % OUT_DIM;
        float s = cvec[o];
        for (int k = 0; k < HID; ++k) s += lds_h[r][k] * A[o*HID + k];
        out[(size_t)(b0 + r) * OUT_DIM + o] = s;
    }
}

extern "C" void kernel_launch(void* const* d_in, const int* in_sizes, int n_in,
                              void* d_out, int out_size, void* d_ws, size_t ws_size,
                              hipStream_t stream) {
    const float* x  = (const float*)d_in[0];
    const float* H  = (const float*)d_in[1];
    const float* U  = (const float*)d_in[2];
    const float* A  = (const float*)d_in[3];
    const float* b  = (const float*)d_in[4];
    const float* c  = (const float*)d_in[5];
    float* out = (float*)d_out;

    rnn_kernel<<<dim3(BATCH / BB), dim3(1024), 0, stream>>>(x, H, U, A, b, c, out);
}

// Round 10
// 475.225 us; speedup vs baseline: 1.2483x; 1.2483x over previous
//
#include <hip/hip_runtime.h>

// SimpleRNN: h_{t+1} = tanh(h_t @ H^T + x_t @ U + b); out = h_T @ A^T + c
// T=512 B=2048 IN=28 HID=198 OUT=10, all fp32.
//
// R10 = R8 (best: 358us) + latency cuts. R9 lesson: DPP operand rebuild put
// VALU serially on the load->MFMA path and regressed; R8's paired
// same-address reads are already free broadcasts (m136), reads cost ~6cyc.
// The remaining ~700cyc/step constant is barrier-convoy latency, attacked by:
//  1. Stager 2-deep pipeline: at step t, ds_write the x[t+1] data loaded at
//     step t-1 (no vmcnt stall), then issue the x[t+2] load (drains next
//     step, ~1600cyc later). HBM latency leaves the barrier path.
//  2. 4 MFMA chains of depth 2 (slot c and c+4 -> acc[c]) + pairwise adds:
//     halves exposed MFMA dependency latency per step.
//
// Structure: persistent, grid=256 (1 block/CU), BB=8 rows/block, 1024 thr =
// 16 waves (4/SIMD). Waves 0-12: one 16-col N-tile each, fp16 single-pass
// recurrence (8 MFMAs), x@U folded as K-slot 7 with B=U. Wave 15: stager.
// A-frag dedup layout [buf][slot][chunk*8+r8][8] fp16; lanes m,m+8 broadcast.
// Epilogue: rows spread over quads, 2 tanh + 2 ds_write_b16 per lane.
// One __syncthreads per step.

#define T_STEPS 512
#define BATCH   2048
#define IN_DIM  28
#define HID     198
#define OUT_DIM 10
#define BB      8    // batch rows per block
#define KT      8    // 7 H k-tiles of 32 (224 >= 198) + 1 U/x slot
#define NCW     13   // compute waves / N-tiles

typedef __attribute__((ext_vector_type(8))) _Float16 half8;
typedef __attribute__((ext_vector_type(4))) float   floatx4;

__device__ __forceinline__ floatx4 mfma16(half8 a, half8 b, floatx4 c) {
    return __builtin_amdgcn_mfma_f32_16x16x32_f16(a, b, c, 0, 0, 0);
}

// tanh(x) = 1 - 2/(exp(2x)+1); exp2-based, saturates via IEEE inf/0.
__device__ __forceinline__ float fast_tanh(float x) {
    float e = __builtin_amdgcn_exp2f(x * 2.885390081777926357f); // exp(2x)
    float r = __builtin_amdgcn_rcpf(e + 1.0f);
    return __builtin_fmaf(-2.0f, r, 1.0f);
}

__global__ void __launch_bounds__(1024, 4)
rnn_kernel(const float* __restrict__ x, const float* __restrict__ H,
           const float* __restrict__ U, const float* __restrict__ A,
           const float* __restrict__ bvec, const float* __restrict__ cvec,
           float* __restrict__ out)
{
    // Dedup A-frag ping-pong: [buf][slot][chunk*8 + r8][idx], fp16, 512B/slot.
    __shared__ __align__(16) _Float16 lds_A[2][KT][32][8];   // 8 KB
    __shared__ float lds_h[BB][204];                          // final h, fp32

    const int tid  = threadIdx.x;
    const int lane = tid & 63;
    const int wv   = tid >> 6;          // wave id 0..15
    const int m    = lane & 15;         // A-row / C-col index within tile
    const int quad = lane >> 4;         // 0..3
    const int r8   = m & 7;
    const int b0   = blockIdx.x * BB;

    // zero-init both buffers (h0 = 0; phantom K rows stay 0 forever)
    {
        _Float16* p0 = &lds_A[0][0][0][0];
        for (int i = tid; i < 2*KT*32*8; i += 1024) p0[i] = (_Float16)0.0f;
    }
    __syncthreads();   // zero-fill complete before stager prologue writes

    floatx4 zero4 = {0.0f, 0.0f, 0.0f, 0.0f};

    // ---- compute-wave setup: stationary fp16 B fragments (H + U) ----
    half8 Bf[KT];
    float bias_eff = 0.0f;
    int   jcol = 0, e_ktd = 0, e_chunk8 = 0, e_idx = 0;
    bool  e_wr = false;
    if (wv < NCW) {
        jcol = wv*16 + m;                               // output column (>=198 phantom)
        bias_eff = (jcol < HID) ? bvec[jcol] : 0.0f;
        #pragma unroll
        for (int kt = 0; kt < 7; ++kt) {
            half8 f;
            #pragma unroll
            for (int idx = 0; idx < 8; ++idx) {
                int k = kt*32 + quad*8 + idx;
                float v = (jcol < HID && k < HID) ? H[jcol*HID + k] : 0.0f; // B[k][j]=H[j][k]
                f[idx] = (_Float16)v;
            }
            Bf[kt] = f;
        }
        {   // slot 7: U
            half8 f;
            #pragma unroll
            for (int idx = 0; idx < 8; ++idx) {
                int i = quad*8 + idx;
                float v = (jcol < HID && i < IN_DIM) ? U[i*HID + jcol] : 0.0f;
                f[idx] = (_Float16)v;
            }
            Bf[7] = f;
        }
        e_ktd    = jcol >> 5;
        e_chunk8 = ((jcol & 31) >> 3) * 8;
        e_idx    = jcol & 7;
        e_wr     = (jcol < HID);
    }

    // ---- epilogue row split: all 4 quads cover the 8 real C rows ----
    // quad0: regs {0,1} -> rows {0,1}; quad1: regs {0,1} -> rows {4,5};
    // quad2: regs {2,3} -> rows {2,3}(+8 dup); quad3: regs {2,3} -> rows {6,7}(+8 dup).
    const int regbase = (quad >> 1) * 2;            // 0 or 2

    // ---- stager setup (wave 15, lanes 0-31): 2-deep pipelined x staging ----
    const int srow  = lane & 31;        // chunk*8 + r8
    const int sq    = srow >> 3;        // k-chunk 0..3
    const int sr8   = srow & 7;         // batch row
    const float* xrow_s = x + (size_t)(b0 + sr8) * IN_DIM + sq*8;
    const size_t tstride = (size_t)BATCH * IN_DIM;

    floatx4 pf0 = zero4, pf1 = zero4;   // pending x[t+1] data during step t

    if (wv == 15 && lane < 32) {
        // x[0] -> buffer 0 (one-time, waits for the load)
        floatx4 f0 = *(const floatx4*)xrow_s;
        floatx4 f1 = (sq < 3) ? *(const floatx4*)(xrow_s + 4) : zero4;
        half8 ax;
        ax[0] = (_Float16)f0[0]; ax[1] = (_Float16)f0[1];
        ax[2] = (_Float16)f0[2]; ax[3] = (_Float16)f0[3];
        ax[4] = (_Float16)f1[0]; ax[5] = (_Float16)f1[1];
        ax[6] = (_Float16)f1[2]; ax[7] = (_Float16)f1[3];
        *(half8*)&lds_A[0][7][srow][0] = ax;
        // issue load of x[1] -> pending (drains during step 0)
        const float* p = xrow_s + tstride;
        pf0 = *(const floatx4*)p;
        pf1 = (sq < 3) ? *(const floatx4*)(p + 4) : zero4;
    }

    // ================= time loop =================
    #pragma unroll 1
    for (int t = 0; t < T_STEPS; ++t) {
        const int rb = t & 1;
        const int wb = rb ^ 1;

        __syncthreads();   // prior writes into rb visible; wb free to write

        if (wv < NCW) {
            // 8 MFMAs in 4 chains of depth 2 (slot c and c+4 share acc[c]).
            floatx4 acc[4];
            acc[0] = (floatx4){bias_eff, bias_eff, bias_eff, bias_eff};
            acc[1] = zero4; acc[2] = zero4; acc[3] = zero4;
            #pragma unroll
            for (int kt = 0; kt < KT; ++kt) {
                half8 a = *(const half8*)&lds_A[rb][kt][quad*8 + r8][0];
                acc[kt & 3] = mfma16(a, Bf[kt], acc[kt & 3]);
            }
            floatx4 s4 = (acc[0] + acc[1]) + (acc[2] + acc[3]);
            // epilogue: 2 tanh + 2 fp16 writes per lane (rows split over quads)
            if (e_wr) {
                #pragma unroll
                for (int e = 0; e < 2; ++e) {
                    const int reg = regbase + e;
                    const int row = (quad & 1) * 4 + reg;   // 0..7, all 8 covered
                    float v = fast_tanh(s4[reg]);
                    lds_A[wb][e_ktd][e_chunk8 + row][e_idx] = (_Float16)v;
                    if (t == T_STEPS - 1) lds_h[row][jcol] = v;
                }
            }
        } else if (wv == 15 && lane < 32) {
            // write x[t+1] (loaded a step ago; vmcnt already drained or nearly so)
            half8 ax;
            ax[0] = (_Float16)pf0[0]; ax[1] = (_Float16)pf0[1];
            ax[2] = (_Float16)pf0[2]; ax[3] = (_Float16)pf0[3];
            ax[4] = (_Float16)pf1[0]; ax[5] = (_Float16)pf1[1];
            ax[6] = (_Float16)pf1[2]; ax[7] = (_Float16)pf1[3];
            *(half8*)&lds_A[wb][7][srow][0] = ax;
            // issue load of x[t+2] -> pending (drains during step t+1)
            const int tn = (t + 2 < T_STEPS) ? (t + 2) : (T_STEPS - 1);
            const float* p = xrow_s + (size_t)tn * tstride;
            pf0 = *(const floatx4*)p;
            pf1 = (sq < 3) ? *(const floatx4*)(p + 4) : zero4;
        }
        // waves 13,14 + lanes 32-63 of wave 15: barrier only
    }

    __syncthreads();

    // ---- output: out[b][o] = sum_k h[b][k]*A[o][k] + c[o] (tiny, scalar) ----
    if (tid < BB * OUT_DIM) {
        const int r = tid / OUT_DIM;
        const int o = tid % OUT_DIM;
        float s = cvec[o];
        for (int k = 0; k < HID; ++k) s += lds_h[r][k] * A[o*HID + k];
        out[(size_t)(b0 + r) * OUT_DIM + o] = s;
    }
}

extern "C" void kernel_launch(void* const* d_in, const int* in_sizes, int n_in,
                              void* d_out, int out_size, void* d_ws, size_t ws_size,
                              hipStream_t stream) {
    const float* x  = (const float*)d_in[0];
    const float* H  = (const float*)d_in[1];
    const float* U  = (const float*)d_in[2];
    const float* A  = (const float*)d_in[3];
    const float* b  = (const float*)d_in[4];
    const float* c  = (const float*)d_in[5];
    float* out = (float*)d_out;

    rnn_kernel<<<dim3(BATCH / BB), dim3(1024), 0, stream>>>(x, H, U, A, b, c, out);
}